// Round 6
// baseline (472.138 us; speedup 1.0000x reference)
//
#include <hip/hip_runtime.h>

#define NB    133
#define NBP   136
#define NJP   168            // wL/gTl j-stride in shorts: 21x16B chunks, odd multiple -> uniform banks on b128
#define BATCH 256
#define HEADS 8
#define CDIM  128
#define DDIM  1024
#define MROWS (BATCH * NB)   // 34048 = 266*128
#define NDIM  (HEADS * CDIM)
#define BH    (BATCH * HEADS)
#define NKT   32             // K tiles of BK=32

typedef __bf16 bf16_t;
typedef bf16_t bf16x8 __attribute__((ext_vector_type(8)));
typedef float  f32x4  __attribute__((ext_vector_type(4)));

__device__ __forceinline__ unsigned short f2bf(float f) {
  unsigned u = __float_as_uint(f);
  u += 0x7fffu + ((u >> 16) & 1u);
  return (unsigned short)(u >> 16);
}
__device__ __forceinline__ void load_lds16(const void* g, void* l) {
  __builtin_amdgcn_global_load_lds(
      (__attribute__((address_space(1))) void*)(g),
      (__attribute__((address_space(3))) void*)(l), 16, 0, 0);
}
__device__ __forceinline__ void bar() {
  asm volatile("" ::: "memory");
  __builtin_amdgcn_s_barrier();
  asm volatile("" ::: "memory");
}
#define VMWAIT(n) asm volatile("s_waitcnt vmcnt(" #n ")" ::: "memory")

// ---------------- fp32 -> bf16 convert, x and W in one launch ----------------
__global__ __launch_bounds__(256) void cvt_kernel(const float* __restrict__ x,
                                                  const float* __restrict__ W,
                                                  unsigned short* __restrict__ xb,
                                                  unsigned short* __restrict__ wb) {
  const int nx = MROWS * DDIM / 8, nw = NDIM * DDIM / 8;
  int i = blockIdx.x * 256 + threadIdx.x;
  const float* src; unsigned short* dst; int k;
  if (i < nx)           { src = x; dst = xb; k = i; }
  else if (i < nx + nw) { src = W; dst = wb; k = i - nx; }
  else return;
  const float4* s4 = (const float4*)src;
  float4 a = s4[(size_t)k * 2];
  float4 b = s4[(size_t)k * 2 + 1];
  union { unsigned short u[8]; uint4 v; } p;
  p.u[0] = f2bf(a.x); p.u[1] = f2bf(a.y); p.u[2] = f2bf(a.z); p.u[3] = f2bf(a.w);
  p.u[4] = f2bf(b.x); p.u[5] = f2bf(b.y); p.u[6] = f2bf(b.z); p.u[7] = f2bf(b.w);
  ((uint4*)dst)[k] = p.v;
}

// ---------------- adjacency bitmasks, one block per row/col ----------------
__global__ __launch_bounds__(192) void mask_kernel(const float* __restrict__ adj,
                                                   unsigned* __restrict__ rm,
                                                   unsigned* __restrict__ cm) {
  const int tid = threadIdx.x, lane = tid & 63, wv = tid >> 6, blk = blockIdx.x;
  if (blk < 144) {
    const int i = blk;
    bool on = (i < NB) && (tid < NB) && (adj[i * NB + tid] != 0.f);
    unsigned long long bb = __ballot(on);
    if (lane == 0)  rm[i * 6 + wv * 2]     = (unsigned)bb;
    if (lane == 32) rm[i * 6 + wv * 2 + 1] = (unsigned)(bb >> 32);
  } else {
    const int j = blk - 144;
    bool on = (tid < NB) && (adj[tid * NB + j] != 0.f);
    unsigned long long bb = __ballot(on);
    if (lane == 0)  cm[j * 6 + wv * 2]     = (unsigned)bb;
    if (lane == 32) cm[j * 6 + wv * 2 + 1] = (unsigned)(bb >> 32);
  }
}

// ---------------- GEMM: g = x @ W^T, fused si/sj ----------------
// R4 structure (A+B in LDS, ring-3, 2 phases/K-tile, counted vmcnt(6)) with the
// PROVEN R0/R2 swizzle restored: slot s of row r holds chunk s ^ ((r>>1)&3)
// (staging XOR = (f>>3)&3, read slot = q ^ ((li>>1)&3)) -- measured ZERO bank
// conflicts in R0/R2; R3-R5 had an indexing slip ((f>>2)/(f>>4)) costing
// 4 extra cycles per b128 read.
__global__ __launch_bounds__(256, 2) void gemm_kernel(const unsigned short* __restrict__ xb,
                                                      const unsigned short* __restrict__ wb,
                                                      const float* __restrict__ attn_w,
                                                      unsigned short* __restrict__ gb,
                                                      float* __restrict__ si_ws,
                                                      float* __restrict__ sj_ws) {
  __shared__ __attribute__((aligned(16))) unsigned short Abuf[3][128 * 32];
  __shared__ __attribute__((aligned(16))) unsigned short Bbuf[3][256 * 32];
  __shared__ float sred[2][4][128];

  const int tid = threadIdx.x;
  // bijective XCD swizzle: nwg = 1064 = 8*133 exactly.
  const int orig = blockIdx.x;
  const int wg = (orig & 7) * 133 + (orig >> 3);
  const int bn = wg & 3, bm = wg >> 2;            // 266 m-tiles x 4 n-tiles

  const int lane = tid & 63, w = tid >> 6;        // wave w: cols w*64, rows 0..127
  const int q = lane >> 4, li = lane & 15;

  const unsigned short* Ab = xb + (size_t)bm * 128 * DDIM;
  const unsigned short* Bb = wb + (size_t)bn * 256 * DDIM;

  // staging: flat chunk f = tid + i*256; row = f>>2, lds slot = f&3,
  // source chunk = slot ^ ((row>>1)&3) = (f&3) ^ ((f>>3)&3)  [proven R0 form]
  int sA[2], sB[4];
#pragma unroll
  for (int i = 0; i < 2; ++i) {
    const int f = tid + i * 256;
    sA[i] = (f >> 2) * DDIM + (((f & 3) ^ ((f >> 3) & 3)) << 3);
  }
#pragma unroll
  for (int i = 0; i < 4; ++i) {
    const int f = tid + i * 256;
    sB[i] = (f >> 2) * DDIM + (((f & 3) ^ ((f >> 3) & 3)) << 3);
  }
#define STGA(buf_, kt_) do { \
    load_lds16(Ab + sA[0] + (kt_) * 32, &Abuf[buf_][tid * 8]); \
    load_lds16(Ab + sA[1] + (kt_) * 32, &Abuf[buf_][(tid + 256) * 8]); \
  } while (0)
#define STGB(buf_, kt_) do { \
    load_lds16(Bb + sB[0] + (kt_) * 32, &Bbuf[buf_][tid * 8]); \
    load_lds16(Bb + sB[1] + (kt_) * 32, &Bbuf[buf_][(tid + 256) * 8]); \
    load_lds16(Bb + sB[2] + (kt_) * 32, &Bbuf[buf_][(tid + 512) * 8]); \
    load_lds16(Bb + sB[3] + (kt_) * 32, &Bbuf[buf_][(tid + 768) * 8]); \
  } while (0)

  // frag reads: slot = q ^ ((li>>1)&3)  [proven R0 form, 0 conflicts measured]
  const int asl = (q ^ ((li >> 1) & 3)) << 3;

  f32x4 acc[8][4] = {};
  bf16x8 a[8], bf01[2], bf23[2];

  // prologue: tiles 0,1 staged (12 loads); wait tile0 (tile1's 6 in flight)
  STGA(0, 0); STGB(0, 0);
  STGA(1, 1); STGB(1, 1);
  VMWAIT(6);
  bar();

  for (int t = 0; t < NKT; ++t) {
    const int cur = t % 3, nxt = (t + 2) % 3;
    const unsigned short* As = &Abuf[cur][0];
    const unsigned short* Bs = &Bbuf[cur][0];
    // P1: A frags (8) + B frags ni 0,1 (2)
#pragma unroll
    for (int mi = 0; mi < 8; ++mi)
      a[mi] = *(const bf16x8*)&As[(mi * 16 + li) * 32 + asl];
#pragma unroll
    for (int ni = 0; ni < 2; ++ni)
      bf01[ni] = *(const bf16x8*)&Bs[(w * 64 + ni * 16 + li) * 32 + asl];
    bar();
    __builtin_amdgcn_s_setprio(1);
#pragma unroll
    for (int mi = 0; mi < 8; ++mi)
#pragma unroll
      for (int ni = 0; ni < 2; ++ni)
        acc[mi][ni] = __builtin_amdgcn_mfma_f32_16x16x32_bf16(a[mi], bf01[ni], acc[mi][ni], 0, 0, 0);
    __builtin_amdgcn_s_setprio(0);
    // P2: B frags ni 2,3 (2) + stage tile t+2 into ring slot (t+2)%3 (the
    // buffer tile t-1 consumed; WAR-safe by barrier separation); counted wait
    // drains tile t+1's 6 loads, leaves t+2's 6 in flight.
#pragma unroll
    for (int ni = 0; ni < 2; ++ni)
      bf23[ni] = *(const bf16x8*)&Bs[(w * 64 + (ni + 2) * 16 + li) * 32 + asl];
    if (t < NKT - 2) {
      STGA(nxt, t + 2); STGB(nxt, t + 2);
      VMWAIT(6);
    } else {
      VMWAIT(0);
    }
    bar();
    __builtin_amdgcn_s_setprio(1);
#pragma unroll
    for (int mi = 0; mi < 8; ++mi)
#pragma unroll
      for (int ni = 0; ni < 2; ++ni)
        acc[mi][ni + 2] = __builtin_amdgcn_mfma_f32_16x16x32_bf16(a[mi], bf23[ni], acc[mi][ni + 2], 0, 0, 0);
    __builtin_amdgcn_s_setprio(0);
  }
#undef STGA
#undef STGB

  // ---- fused si/sj: per-head dot with wl/wr; head = bn*2 + (w>>1) ----
  float wlv[4], wrv[4];
#pragma unroll
  for (int ni = 0; ni < 4; ++ni) {
    const int cc = (w & 1) * 64 + ni * 16 + li;   // head-local column
    wlv[ni] = attn_w[cc];
    wrv[ni] = attn_w[CDIM + cc];
  }
#pragma unroll
  for (int mi = 0; mi < 8; ++mi)
#pragma unroll
    for (int rr = 0; rr < 4; ++rr) {
      float pj = 0.f, pi = 0.f;
#pragma unroll
      for (int ni = 0; ni < 4; ++ni) {
        pj += acc[mi][ni][rr] * wlv[ni];
        pi += acc[mi][ni][rr] * wrv[ni];
      }
#pragma unroll
      for (int d = 1; d < 16; d <<= 1) {
        pj += __shfl_xor(pj, d);
        pi += __shfl_xor(pi, d);
      }
      if (li == 0) {
        sred[0][w][mi * 16 + q * 4 + rr] = pj;
        sred[1][w][mi * 16 + q * 4 + rr] = pi;
      }
    }
  __syncthreads();
#pragma unroll
  for (int idx0 = 0; idx0 < 2; ++idx0) {
    const int idx = idx0 * 256 + tid;     // 512 items: 2(which) x 2(hw) x 128(rows)
    const int row = idx & 127;
    const int hw = (idx >> 7) & 1;
    const int which = idx >> 8;
    const float v = sred[which][hw * 2][row] + sred[which][hw * 2 + 1][row];
    const int rg = bm * 128 + row;
    const int b = rg / NB, n = rg - b * NB;
    const int h = bn * 2 + hw;
    float* dst = which ? si_ws : sj_ws;
    dst[(b * HEADS + h) * NB + n] = v;
  }

  // ---- store g bf16, normal [row][col] layout ----
#pragma unroll
  for (int mi = 0; mi < 8; ++mi)
#pragma unroll
    for (int ni = 0; ni < 4; ++ni) {
      const int col = bn * 256 + w * 64 + ni * 16 + li;
      const size_t row0 = (size_t)(bm * 128 + mi * 16 + q * 4);
#pragma unroll
      for (int rr = 0; rr < 4; ++rr)
        gb[(row0 + rr) * NDIM + col] = f2bf(acc[mi][ni][rr]);
    }
}

// ---------------- column softmax stats: smrg[bh][j] = (sj_j, m_j + ln(denom_j)) ----------------
__global__ __launch_bounds__(192) void stats_kernel(const float* __restrict__ si_ws,
                                                    const float* __restrict__ sj_ws,
                                                    const unsigned* __restrict__ cm,
                                                    float2* __restrict__ smrg) {
  __shared__ float siL[NB];
  const int tid = threadIdx.x;
  const int base = blockIdx.x * NB;
  if (tid < NB) siL[tid] = si_ws[base + tid];
  __syncthreads();
  if (tid >= 160) return;
  float2 o = {0.f, 0.f};
  if (tid < NB) {
    const int j = tid;
    const float sjv = sj_ws[base + j];
    float m = -3.0e38f;
#pragma unroll
    for (int wd = 0; wd < 5; ++wd) {
      unsigned bits = cm[j * 6 + wd];
      while (bits) {
        const int i = __ffs(bits) - 1; bits &= bits - 1;
        float e = siL[wd * 32 + i] + sjv;
        e = e > 0.f ? e : 0.2f * e;
        m = fmaxf(m, e);
      }
    }
    float s = 0.f;
#pragma unroll
    for (int wd = 0; wd < 5; ++wd) {
      unsigned bits = cm[j * 6 + wd];
      while (bits) {
        const int i = __ffs(bits) - 1; bits &= bits - 1;
        float e = siL[wd * 32 + i] + sjv;
        e = e > 0.f ? e : 0.2f * e;
        s += __expf(e - m);
      }
    }
    o.x = sjv;
    o.y = m + __logf(s);   // weight = exp(e - o.y): rd folded into the exponent
  }
  smrg[(size_t)blockIdx.x * 160 + tid] = o;
}

// ---------------- aggregation: block = (b,h); weights computed ONCE into LDS ----------------
// Old version recomputed each softmax weight ~2.6x (64-lane overlap x 2 f-half
// blocks) inside the MFMA A-fragment build. New: 2048 blocks x 512 threads;
// phase 1 builds wL[i][j] bf16 (each (i,j) exp exactly once, packed uint
// stores) + gTl[f][j] transpose + zero pads; phase 2 is a lean MFMA sweep:
// per wave (f-slice of 16): 5 hoisted B-frags + 9 mt x {5 A-frags, 5 MFMA}.
// Stride NJP=168 shorts = 21x16B (odd multiple) -> uniform bank spread on the
// b128 frag reads. j>=133 and i>=133 weight rows/cols zeroed -> padded K=160
// MFMA contributes exact zeros.
__global__ __launch_bounds__(512) void agg_kernel(const unsigned short* __restrict__ gb,
                                                  const float* __restrict__ si_ws,
                                                  const float2* __restrict__ smrg,
                                                  const unsigned* __restrict__ rm,
                                                  float* __restrict__ out) {
  __shared__ __attribute__((aligned(16))) unsigned short wLs[144 * NJP]; // [i][j] weights
  __shared__ __attribute__((aligned(16))) unsigned short gTl[128 * NJP]; // [f][j]
  const int tid = threadIdx.x;
  const int bh = blockIdx.x;
  const int b = bh >> 3, h = bh & 7;
  const int base = bh * NB;
  const float2* smr = smrg + (size_t)bh * 160;

  // -- pads (disjoint from fills; no barrier needed among phase-1 writers) --
  for (int e = tid; e < 133 * 17; e += 512) {        // wL rows<133, shorts 134..167
    const int i = e / 17, t = e - i * 17;
    *(unsigned*)&wLs[i * NJP + 134 + 2 * t] = 0;
  }
  for (int e = tid; e < 11 * 84; e += 512) {         // wL rows 133..143, all
    const int r = 133 + e / 84, t = e - (e / 84) * 84;
    *(unsigned*)&wLs[r * NJP + 2 * t] = 0;
  }
  for (int e = tid; e < 128 * 18; e += 512) {        // gTl shorts 133..167
    const int f = e / 18, k = e - f * 18;
    if (k == 0) wLs[0] += 0, gTl[f * NJP + 133] = 0;
    else *(unsigned*)&gTl[f * NJP + 132 + 2 * k] = 0;
  }

  // -- weights: each (i, j-pair) exactly once; identical arithmetic to old --
  for (int e = tid; e < 133 * 67; e += 512) {
    const int i = e / 67, jp = e - i * 67;
    const int j0 = jp * 2;
    const float si_r = si_ws[base + i];
    const unsigned bits = rm[i * 6 + (j0 >> 5)];
    float v0, v1;
    {
      const float2 sv = smr[j0];
      float ee = si_r + sv.x;
      ee = ee > 0.f ? ee : 0.2f * ee;
      v0 = ((bits >> (j0 & 31)) & 1u) ? __expf(ee - sv.y) : 0.f;
    }
    if (j0 + 1 < 133) {
      const float2 sv = smr[j0 + 1];
      float ee = si_r + sv.x;
      ee = ee > 0.f ? ee : 0.2f * ee;
      v1 = ((bits >> ((j0 + 1) & 31)) & 1u) ? __expf(ee - sv.y) : 0.f;
    } else v1 = 0.f;
    *(unsigned*)&wLs[i * NJP + j0] = (unsigned)f2bf(v0) | ((unsigned)f2bf(v1) << 16);
  }

  // -- transpose g slice: [j][f] -> gTl[f][j], coalesced 8B reads --
  const unsigned short* gsrc = gb + (size_t)(b * NB) * NDIM + h * CDIM;
  for (int u = tid; u < NB * 32; u += 512) {
    const int j = u >> 5, fg = u & 31;
    const uint2 d = *(const uint2*)(gsrc + (size_t)j * NDIM + fg * 4);
    const int f0 = fg * 4;
    gTl[(f0 + 0) * NJP + j] = (unsigned short)(d.x);
    gTl[(f0 + 1) * NJP + j] = (unsigned short)(d.x >> 16);
    gTl[(f0 + 2) * NJP + j] = (unsigned short)(d.y);
    gTl[(f0 + 3) * NJP + j] = (unsigned short)(d.y >> 16);
  }
  __syncthreads();

  // -- MFMA sweep: wave wv owns f-slice wv*16..+15 --
  const int lane = tid & 63, wv = tid >> 6, q = lane >> 4, li = lane & 15;
  const int f0 = wv * 16;
  bf16x8 bv[5];
#pragma unroll
  for (int ks = 0; ks < 5; ++ks)
    bv[ks] = *(const bf16x8*)&gTl[(f0 + li) * NJP + ks * 32 + q * 8];
  float* obase = out + (size_t)(b * NB) * NDIM + h * CDIM + f0;
#pragma unroll
  for (int mt = 0; mt < 9; ++mt) {
    f32x4 acc = {};
#pragma unroll
    for (int ks = 0; ks < 5; ++ks) {
      const bf16x8 av = *(const bf16x8*)&wLs[(mt * 16 + li) * NJP + ks * 32 + q * 8];
      acc = __builtin_amdgcn_mfma_f32_16x16x32_bf16(av, bv[ks], acc, 0, 0, 0);
    }
#pragma unroll
    for (int rr = 0; rr < 4; ++rr) {
      const int i = mt * 16 + q * 4 + rr;
      if (i < NB) obase[(size_t)i * NDIM + li] = acc[rr];
    }
  }
}

extern "C" void kernel_launch(void* const* d_in, const int* in_sizes, int n_in,
                              void* d_out, int out_size, void* d_ws, size_t ws_size,
                              hipStream_t stream) {
  const float* x      = (const float*)d_in[0];
  const float* W      = (const float*)d_in[1];
  const float* attn_w = (const float*)d_in[2];
  const float* adj    = (const float*)d_in[3];
  float* out = (float*)d_out;
  char* ws = (char*)d_ws;

  // workspace layout (bytes), ~143.7 MB; smrg overlays xb (xb dead after gemm)
  unsigned short* xb = (unsigned short*)(ws + 0);            // 69,730,304
  unsigned short* wb = (unsigned short*)(ws + 69730304);     //  2,097,152
  unsigned short* gb = (unsigned short*)(ws + 71827456);     // 69,730,304
  float* si = (float*)(ws + 141557760);                      //  1,089,536
  float* sj = (float*)(ws + 142647296);                      //  1,089,536
  unsigned* rm = (unsigned*)(ws + 143736832);                //      3,456
  unsigned* cm = (unsigned*)(ws + 143740288);                //      3,192
  float2* smrg = (float2*)(ws + 0);                          //  2,621,440 (overlay)

  const int ncvt = (MROWS * DDIM + NDIM * DDIM) / 8;
  cvt_kernel<<<(ncvt + 255) / 256, 256, 0, stream>>>(x, W, xb, wb);
  mask_kernel<<<277, 192, 0, stream>>>(adj, rm, cm);
  gemm_kernel<<<266 * 4, 256, 0, stream>>>(xb, wb, attn_w, gb, si, sj);
  stats_kernel<<<BH, 192, 0, stream>>>(si, sj, cm, smrg);
  agg_kernel<<<BH, 512, 0, stream>>>(gb, si, smrg, rm, out);
}